// Round 3
// baseline (334.965 us; speedup 1.0000x reference)
//
#include <hip/hip_runtime.h>
#include <hip/hip_bf16.h>

typedef __bf16 bf16x8 __attribute__((ext_vector_type(8)));
typedef float floatx4 __attribute__((ext_vector_type(4)));

#define LDW 136  // row stride (272B = 17*16B: b128-aligned, 8 bank-quads/16 lanes)

// transposed-weight workspace layout (bf16 element offsets): Wt[n][k]
#define O_E1W2  0
#define O_E2W1  16384
#define O_E2W2  49152
#define O_E3W1  65536
#define O_E3W2  81920
#define O_E4W1  98304
#define O_E4W2  131072
#define O_DM2T0 147456
#define O_DM2T1 163840
#define O_DO1   180224
#define O_DO2   196608
#define O_EWOUT 212992   // [16 pad][128], rows 0,1 = ew_out^T
#define O_DW3   215040   // [16 pad][128], rows 0..2 = d_out_w3^T
#define WS_ELEMS 217088

// f32 w[k][n] -> bf16 Wt[n][k]; branch/shift only, no division.
__global__ void prep_kernel(const float* e1w2, const float* e2w1, const float* e2w2,
    const float* e3w1, const float* e3w2, const float* e4w1, const float* e4w2,
    const float* dmsg2, const float* dout1, const float* dout2,
    const float* ew_out, const float* dout_w3, __hip_bfloat16* ws) {
  int idx = blockIdx.x * 256 + threadIdx.x;
  if (idx >= WS_ELEMS) return;
  float v;
  if (idx < O_E2W1)      { int l = idx;           v = e1w2[(l & 127) * 128 + (l >> 7)]; }
  else if (idx < O_E2W2) { int l = idx - O_E2W1;  v = e2w1[(l & 255) * 128 + (l >> 8)]; }
  else if (idx < O_E3W1) { int l = idx - O_E2W2;  v = e2w2[(l & 127) * 128 + (l >> 7)]; }
  else if (idx < O_E3W2) { int l = idx - O_E3W1;  v = e3w1[(l & 127) * 128 + (l >> 7)]; }
  else if (idx < O_E4W1) { int l = idx - O_E3W2;  v = e3w2[(l & 127) * 128 + (l >> 7)]; }
  else if (idx < O_E4W2) { int l = idx - O_E4W1;  v = e4w1[(l & 255) * 128 + (l >> 8)]; }
  else if (idx < O_DM2T0){ int l = idx - O_E4W2;  v = e4w2[(l & 127) * 128 + (l >> 7)]; }
  else if (idx < O_DM2T1){ int l = idx - O_DM2T0; v = dmsg2[(l & 127) * 128 + (l >> 7)]; }
  else if (idx < O_DO1)  { int l = idx - O_DM2T1; v = dmsg2[16384 + (l & 127) * 128 + (l >> 7)]; }
  else if (idx < O_DO2)  { int l = idx - O_DO1;   v = dout1[384 + (l & 127) * 128 + (l >> 7)]; }
  else if (idx < O_EWOUT){ int l = idx - O_DO2;   v = dout2[(l & 127) * 128 + (l >> 7)]; }
  else if (idx < O_DW3)  { int l = idx - O_EWOUT; int n = l >> 7;
                           v = (n < 2) ? ew_out[(l & 127) * 2 + n] : 0.f; }
  else                   { int l = idx - O_DW3;   int n = l >> 7;
                           v = (n < 3) ? dout_w3[(l & 127) * 3 + n] : 0.f; }
  ws[idx] = __float2bfloat16(v);
}

// 8 graphs/WG -> 48 rows; LDS ~37.5KB -> 4 blocks/CU (16 waves).
__global__ __launch_bounds__(256, 4) void nri_fused(
    const float* __restrict__ x,
    const float* __restrict__ e1w1, const float* __restrict__ e1b1,
    const float* __restrict__ e1b2, const float* __restrict__ e2b1,
    const float* __restrict__ e2b2, const float* __restrict__ e3b1,
    const float* __restrict__ e3b2, const float* __restrict__ e4b1,
    const float* __restrict__ e4b2, const float* __restrict__ eb_out,
    const float* __restrict__ dmsg_w1, const float* __restrict__ dmsg_b1,
    const float* __restrict__ dmsg_b2, const float* __restrict__ dout_w1,
    const float* __restrict__ dout_b1, const float* __restrict__ dout_b2,
    const float* __restrict__ dout_b3, const __bf16* __restrict__ wt,
    float* __restrict__ out)
{
  const int tid  = threadIdx.x;
  const int wave = tid >> 6;
  const int lane = tid & 63;
  const int nl   = lane & 15;
  const int quad = lane >> 4;

  __shared__ __align__(16) __hip_bfloat16 bufA[48 * LDW];
  __shared__ __align__(16) __hip_bfloat16 bufB[48 * LDW];
  __shared__ float xs[144];    // x block [8][6][3]
  __shared__ float rt[96];     // logits -> softmax weights [48][2]
  __shared__ float wE1[512];   // e1w1[3*128] + e1b1[128]
  __shared__ float wM1[1792];  // d_msg_w1[2][6][128] + d_msg_b1[2][128]
  __shared__ float wD1x[384];  // d_out_w1 rows 0..2
  __shared__ float obuf[144];  // staged output

  // ---- stage 0: stage x + small f32 weights ----
  if (tid < 144) xs[tid] = x[blockIdx.x * 144 + tid];
  for (int i = tid; i < 512; i += 256) wE1[i] = (i < 384 ? e1w1[i] : e1b1[i - 384]);
  for (int i = tid; i < 1792; i += 256) {
    int t = i >> 10 ? 1 : (i >= 896);  // i/896
    int l = i - t * 896;
    wM1[i] = (l < 768 ? dmsg_w1[t * 768 + l] : dmsg_b1[t * 128 + (l - 768)]);
  }
  for (int i = tid; i < 384; i += 256) wD1x[i] = dout_w1[i];
  __syncthreads();

  auto initb = [&](floatx4 (&a)[3][2], const float* bias) {
#pragma unroll
    for (int nt = 0; nt < 2; ++nt) {
      float bv = bias[wave * 32 + nt * 16 + nl];
      floatx4 v = {bv, bv, bv, bv};
#pragma unroll
      for (int mt = 0; mt < 3; ++mt) a[mt][nt] = v;
    }
  };

  auto gemm128 = [&](floatx4 (&acc)[3][2], const __hip_bfloat16* in, bool recv,
                     const __bf16* w) {
    int rofs[3];
#pragma unroll
    for (int mt = 0; mt < 3; ++mt) {
      int r = mt * 16 + nl;
      if (recv) { int e = r % 6; r += (e == 5) ? -5 : 1; }
      rofs[mt] = r * LDW;
    }
    const __bf16* ab = (const __bf16*)(const void*)in;
    const __bf16* w0 = w + (wave * 32 + nl) * 128 + quad * 8;
    const __bf16* w1 = w0 + 16 * 128;
#pragma unroll
    for (int ks = 0; ks < 4; ++ks) {
      int kk = ks * 32 + quad * 8;
      bf16x8 b0 = *(const bf16x8*)(w0 + ks * 32);
      bf16x8 b1 = *(const bf16x8*)(w1 + ks * 32);
#pragma unroll
      for (int mt = 0; mt < 3; ++mt) {
        bf16x8 a = *(const bf16x8*)(ab + rofs[mt] + kk);
        acc[mt][0] = __builtin_amdgcn_mfma_f32_16x16x32_bf16(a, b0, acc[mt][0], 0, 0, 0);
        acc[mt][1] = __builtin_amdgcn_mfma_f32_16x16x32_bf16(a, b1, acc[mt][1], 0, 0, 0);
      }
    }
  };

  auto gemm256 = [&](floatx4 (&acc)[3][2], const __hip_bfloat16* in0, bool recv0,
                     const __hip_bfloat16* in1, const __bf16* w) {
    int rofs0[3], rofs1[3];
#pragma unroll
    for (int mt = 0; mt < 3; ++mt) {
      int r = mt * 16 + nl;
      rofs1[mt] = r * LDW;
      if (recv0) { int e = r % 6; r += (e == 5) ? -5 : 1; }
      rofs0[mt] = r * LDW;
    }
    const __bf16* ab0 = (const __bf16*)(const void*)in0;
    const __bf16* ab1 = (const __bf16*)(const void*)in1;
    const __bf16* w0 = w + (wave * 32 + nl) * 256 + quad * 8;
    const __bf16* w1 = w0 + 16 * 256;
#pragma unroll
    for (int ks = 0; ks < 8; ++ks) {
      int kk = (ks & 3) * 32 + quad * 8;
      const __bf16* ab = (ks < 4) ? ab0 : ab1;
      const int* rofs = (ks < 4) ? rofs0 : rofs1;
      bf16x8 b0 = *(const bf16x8*)(w0 + ks * 32);
      bf16x8 b1 = *(const bf16x8*)(w1 + ks * 32);
#pragma unroll
      for (int mt = 0; mt < 3; ++mt) {
        bf16x8 a = *(const bf16x8*)(ab + rofs[mt] + kk);
        acc[mt][0] = __builtin_amdgcn_mfma_f32_16x16x32_bf16(a, b0, acc[mt][0], 0, 0, 0);
        acc[mt][1] = __builtin_amdgcn_mfma_f32_16x16x32_bf16(a, b1, acc[mt][1], 0, 0, 0);
      }
    }
  };

  // activation (1 elu, 2 relu) + bf16 store; bias already in acc
  auto store_act = [&](floatx4 (&acc)[3][2], int act, __hip_bfloat16* ob) {
#pragma unroll
    for (int nt = 0; nt < 2; ++nt) {
      int col = wave * 32 + nt * 16 + nl;
#pragma unroll
      for (int mt = 0; mt < 3; ++mt) {
#pragma unroll
        for (int r = 0; r < 4; ++r) {
          float z = acc[mt][nt][r];
          if (act == 1) z = (z > 0.f) ? z : (__expf(z) - 1.f);
          else z = fmaxf(z, 0.f);
          ob[(mt * 16 + quad * 4 + r) * LDW + col] = __float2bfloat16(z);
        }
      }
    }
  };

  floatx4 acc[3][2];

  // ---- s1 (VALU): ELU(x @ e1w1 + e1b1) -> bufA ----
#pragma unroll 4
  for (int i = 0; i < 24; ++i) {
    int o = i * 256 + tid;
    int row = o >> 7, col = o & 127;
    const float* xr = xs + row * 3;
    float z = wE1[384 + col] + xr[0] * wE1[col] + xr[1] * wE1[128 + col] + xr[2] * wE1[256 + col];
    z = (z > 0.f) ? z : (__expf(z) - 1.f);
    bufA[row * LDW + col] = __float2bfloat16(z);
  }
  __syncthreads();

  // ---- s2: h = ELU(bufA @ e1w2 + e1b2) -> bufB ----
  initb(acc, e1b2); gemm128(acc, bufA, false, wt + O_E1W2);
  store_act(acc, 1, bufB);
  __syncthreads();

  // ---- s3: ELU(concat(h[recv], h) @ e2w1 + e2b1) -> bufA ----
  initb(acc, e2b1); gemm256(acc, bufB, true, bufB, wt + O_E2W1);
  store_act(acc, 1, bufA);
  __syncthreads();

  // ---- s4: he = ELU(bufA @ e2w2 + e2b2) -> bufB (keep) ----
  initb(acc, e2b2); gemm128(acc, bufA, false, wt + O_E2W2);
  store_act(acc, 1, bufB);
  __syncthreads();

  // ---- s5: ELU(he @ e3w1 + e3b1) -> bufA ----
  initb(acc, e3b1); gemm128(acc, bufB, false, wt + O_E3W1);
  store_act(acc, 1, bufA);
  __syncthreads();

  // ---- s6: h2 = ELU(bufA @ e3w2 + e3b2) -> bufA in place ----
  initb(acc, e3b2); gemm128(acc, bufA, false, wt + O_E3W2);
  __syncthreads();
  store_act(acc, 1, bufA);
  __syncthreads();

  // ---- s7: ELU(concat(h2, he) @ e4w1 + e4b1) -> bufA in place ----
  initb(acc, e4b1); gemm256(acc, bufA, false, bufB, wt + O_E4W1);
  __syncthreads();
  store_act(acc, 1, bufA);
  __syncthreads();

  // ---- s8: h3 = ELU(bufA @ e4w2 + e4b2) -> bufB ----
  initb(acc, e4b2); gemm128(acc, bufA, false, wt + O_E4W2);
  store_act(acc, 1, bufB);
  __syncthreads();

  // ---- s9 (MFMA tail): logits = h3 @ ew_out + eb_out -> rt (raw) ----
  if (wave < 3) {
    float bv = (nl < 2) ? eb_out[nl] : 0.f;
    floatx4 lg = {bv, bv, bv, bv};
    const __bf16* ab = (const __bf16*)(const void*)bufB;
    const __bf16* wE = wt + O_EWOUT + nl * 128 + quad * 8;
    int rof = (wave * 16 + nl) * LDW;
#pragma unroll
    for (int ks = 0; ks < 4; ++ks) {
      bf16x8 a = *(const bf16x8*)(ab + rof + ks * 32 + quad * 8);
      bf16x8 b = *(const bf16x8*)(wE + ks * 32);
      lg = __builtin_amdgcn_mfma_f32_16x16x32_bf16(a, b, lg, 0, 0, 0);
    }
    if (nl < 2) {
#pragma unroll
      for (int r = 0; r < 4; ++r) rt[(wave * 16 + quad * 4 + r) * 2 + nl] = lg[r];
    }
  }
  __syncthreads();

  // ---- softmax (tid<48) + m1 both types (all threads): t0->bufA, t1->bufB ----
  if (tid < 48) {
    float l0 = rt[tid * 2], l1 = rt[tid * 2 + 1];
    float mx = fmaxf(l0, l1);
    float ea = __expf(l0 - mx), eb = __expf(l1 - mx);
    float inv = 1.f / (ea + eb);
    rt[tid * 2] = ea * inv; rt[tid * 2 + 1] = eb * inv;
  }
#pragma unroll 4
  for (int i = 0; i < 24; ++i) {
    int o = i * 256 + tid;
    int row = o >> 7, col = o & 127;
    int e = row % 6;
    int rrow = row + ((e == 5) ? -5 : 1);
    const float* xre = xs + rrow * 3;
    const float* xse = xs + row * 3;
    const float* w0 = wM1;
    const float* w1 = wM1 + 896;
    float z0 = w0[768 + col] + xre[0] * w0[col] + xre[1] * w0[128 + col] + xre[2] * w0[256 + col]
             + xse[0] * w0[384 + col] + xse[1] * w0[512 + col] + xse[2] * w0[640 + col];
    float z1 = w1[768 + col] + xre[0] * w1[col] + xre[1] * w1[128 + col] + xre[2] * w1[256 + col]
             + xse[0] * w1[384 + col] + xse[1] * w1[512 + col] + xse[2] * w1[640 + col];
    bufA[row * LDW + col] = __float2bfloat16(fmaxf(z0, 0.f));
    bufB[row * LDW + col] = __float2bfloat16(fmaxf(z1, 0.f));
  }
  __syncthreads();

  // ---- dm2: msg = sum_t rt_t * relu(m1_t @ w2_t + b2_t) ----
  floatx4 msg[3][2];
#pragma unroll
  for (int t = 0; t < 2; ++t) {
    initb(acc, dmsg_b2 + t * 128);
    gemm128(acc, t == 0 ? bufA : bufB, false, wt + (t == 0 ? O_DM2T0 : O_DM2T1));
#pragma unroll
    for (int nt = 0; nt < 2; ++nt)
#pragma unroll
      for (int mt = 0; mt < 3; ++mt)
#pragma unroll
        for (int r = 0; r < 4; ++r) {
          int row = mt * 16 + quad * 4 + r;
          float z = rt[row * 2 + t] * fmaxf(acc[mt][nt][r], 0.f);
          if (t == 0) msg[mt][nt][r] = z; else msg[mt][nt][r] += z;
        }
  }
  __syncthreads();

  // ---- s12: agg (edge e -> node (e+1)%6) -> bufA ----
#pragma unroll
  for (int nt = 0; nt < 2; ++nt) {
    int col = wave * 32 + nt * 16 + nl;
#pragma unroll
    for (int mt = 0; mt < 3; ++mt)
#pragma unroll
      for (int r = 0; r < 4; ++r) {
        int row = mt * 16 + quad * 4 + r;
        int e = row % 6;
        int orow = row + ((e == 5) ? -5 : 1);
        bufA[orow * LDW + col] = __float2bfloat16(msg[mt][nt][r]);
      }
  }
  __syncthreads();

  // ---- s13: p1 = relu(concat(x, agg) @ d_out_w1 + b1) -> bufB ----
  initb(acc, dout_b1);
  gemm128(acc, bufA, false, wt + O_DO1);
#pragma unroll
  for (int nt = 0; nt < 2; ++nt) {
    int col = wave * 32 + nt * 16 + nl;
    float w0 = wD1x[col], w1 = wD1x[128 + col], w2 = wD1x[256 + col];
#pragma unroll
    for (int mt = 0; mt < 3; ++mt)
#pragma unroll
      for (int r = 0; r < 4; ++r) {
        int row = mt * 16 + quad * 4 + r;
        const float* xv = xs + row * 3;
        float z = acc[mt][nt][r] + xv[0] * w0 + xv[1] * w1 + xv[2] * w2;
        bufB[row * LDW + col] = __float2bfloat16(fmaxf(z, 0.f));
      }
  }
  __syncthreads();

  // ---- s14: p2 = relu(bufB @ d_out_w2 + b2) -> bufA ----
  initb(acc, dout_b2); gemm128(acc, bufB, false, wt + O_DO2);
  store_act(acc, 2, bufA);
  __syncthreads();

  // ---- s15 (MFMA tail): out = x + p2 @ d_out_w3 + b3, staged via obuf ----
  if (wave < 3) {
    float bv = (nl < 3) ? dout_b3[nl] : 0.f;
    floatx4 d = {bv, bv, bv, bv};
    const __bf16* ab = (const __bf16*)(const void*)bufA;
    const __bf16* wD = wt + O_DW3 + nl * 128 + quad * 8;
    int rof = (wave * 16 + nl) * LDW;
#pragma unroll
    for (int ks = 0; ks < 4; ++ks) {
      bf16x8 a = *(const bf16x8*)(ab + rof + ks * 32 + quad * 8);
      bf16x8 b = *(const bf16x8*)(wD + ks * 32);
      d = __builtin_amdgcn_mfma_f32_16x16x32_bf16(a, b, d, 0, 0, 0);
    }
    if (nl < 3) {
#pragma unroll
      for (int r = 0; r < 4; ++r) {
        int row = wave * 16 + quad * 4 + r;
        obuf[row * 3 + nl] = xs[row * 3 + nl] + d[r];
      }
    }
  }
  __syncthreads();
  if (tid < 144) out[blockIdx.x * 144 + tid] = obuf[tid];
}

extern "C" void kernel_launch(void* const* d_in, const int* in_sizes, int n_in,
                              void* d_out, int out_size, void* d_ws, size_t ws_size,
                              hipStream_t stream) {
  const float* x       = (const float*)d_in[0];
  const float* e1w1    = (const float*)d_in[3];
  const float* e1b1    = (const float*)d_in[4];
  const float* e1w2    = (const float*)d_in[5];
  const float* e1b2    = (const float*)d_in[6];
  const float* e2w1    = (const float*)d_in[7];
  const float* e2b1    = (const float*)d_in[8];
  const float* e2w2    = (const float*)d_in[9];
  const float* e2b2    = (const float*)d_in[10];
  const float* e3w1    = (const float*)d_in[11];
  const float* e3b1    = (const float*)d_in[12];
  const float* e3w2    = (const float*)d_in[13];
  const float* e3b2    = (const float*)d_in[14];
  const float* e4w1    = (const float*)d_in[15];
  const float* e4b1    = (const float*)d_in[16];
  const float* e4w2    = (const float*)d_in[17];
  const float* e4b2    = (const float*)d_in[18];
  const float* ew_out  = (const float*)d_in[19];
  const float* eb_out  = (const float*)d_in[20];
  const float* dmsg_w1 = (const float*)d_in[21];
  const float* dmsg_b1 = (const float*)d_in[22];
  const float* dmsg_w2 = (const float*)d_in[23];
  const float* dmsg_b2 = (const float*)d_in[24];
  const float* dout_w1 = (const float*)d_in[25];
  const float* dout_b1 = (const float*)d_in[26];
  const float* dout_w2 = (const float*)d_in[27];
  const float* dout_b2 = (const float*)d_in[28];
  const float* dout_w3 = (const float*)d_in[29];
  const float* dout_b3 = (const float*)d_in[30];

  prep_kernel<<<(WS_ELEMS + 255) / 256, 256, 0, stream>>>(
      e1w2, e2w1, e2w2, e3w1, e3w2, e4w1, e4w2, dmsg_w2, dout_w1, dout_w2,
      ew_out, dout_w3, (__hip_bfloat16*)d_ws);

  nri_fused<<<32768 / 8, 256, 0, stream>>>(
      x, e1w1, e1b1, e1b2, e2b1, e2b2, e3b1, e3b2, e4b1, e4b2,
      eb_out, dmsg_w1, dmsg_b1, dmsg_b2,
      dout_w1, dout_b1, dout_b2, dout_b3,
      (const __bf16*)d_ws, (float*)d_out);
}